// Round 1
// baseline (304.331 us; speedup 1.0000x reference)
//
#include <hip/hip_runtime.h>
#include <hip/hip_bf16.h>

// Problem constants
constexpr int Bc  = 2;
constexpr int Tc  = 2048;
constexpr int Ec  = 1024;
constexpr int Hc  = 16;
constexpr int KVc = 4;
constexpr int Dc  = 64;
// G = Hc/KVc = 4

typedef short bf16x8 __attribute__((ext_vector_type(8)));
typedef float f32x4  __attribute__((ext_vector_type(4)));
typedef int   i32x4  __attribute__((ext_vector_type(4)));

__device__ inline short f2bf_bits(float f) {
    union { __hip_bfloat16 h; short s; } u;
    u.h = __float2bfloat16(f);
    return u.s;
}

// ---------------------------------------------------------------------------
// fp32 -> bf16 elementwise convert (vectorized)
// ---------------------------------------------------------------------------
__global__ __launch_bounds__(256) void conv_f32_bf16(
    const float* __restrict__ x, short* __restrict__ y, int n)
{
    int i = (blockIdx.x * 256 + threadIdx.x) * 4;
    if (i >= n) return;
    float4 v = *reinterpret_cast<const float4*>(x + i);
    typedef short short4v __attribute__((ext_vector_type(4)));
    short4v o;
    o[0] = f2bf_bits(v.x);
    o[1] = f2bf_bits(v.y);
    o[2] = f2bf_bits(v.z);
    o[3] = f2bf_bits(v.w);
    *reinterpret_cast<short4v*>(y + i) = o;
}

// ---------------------------------------------------------------------------
// transpose + convert: W[K][N] fp32 -> Wt[N][K] bf16
// ---------------------------------------------------------------------------
__global__ __launch_bounds__(256) void transp_conv(
    const float* __restrict__ W, short* __restrict__ Wt, int K, int N)
{
    __shared__ float tile[32][33];
    int nb = blockIdx.x * 32, kb = blockIdx.y * 32;
    int tx = threadIdx.x & 31, ty = threadIdx.x >> 5;   // ty 0..7
    #pragma unroll
    for (int j = 0; j < 4; ++j)
        tile[ty + j * 8][tx] = W[(size_t)(kb + ty + j * 8) * N + nb + tx];
    __syncthreads();
    #pragma unroll
    for (int j = 0; j < 4; ++j)
        Wt[(size_t)(nb + ty + j * 8) * K + kb + tx] = f2bf_bits(tile[tx][ty + j * 8]);
}

// ---------------------------------------------------------------------------
// bf16 MFMA GEMM: C[M][N] = A[M][K] @ Bt[N][K]^T + bias
// 64x64 tile, BK=64, 4 waves (2x2), each wave 32x32.
// LDS XOR swizzle: elem-col8 ^= (row&7)<<3 (16B-slot swizzle in 128B rows).
// ---------------------------------------------------------------------------
__device__ inline void store_out(short* p, float v)  { *p = f2bf_bits(v); }
__device__ inline void store_out(float* p, float v)  { *p = v; }

template<typename OutT>
__global__ __launch_bounds__(256) void gemm_bf16_nt(
    const short* __restrict__ A,   // [M][K] bf16 bits
    const short* __restrict__ Bt,  // [N][K] bf16 bits
    const float* __restrict__ bias,// [N]
    OutT* __restrict__ C,          // [M][N]
    int M, int N, int K)
{
    __shared__ short As[64 * 64];
    __shared__ short Bs[64 * 64];
    const int tid  = threadIdx.x;
    const int lane = tid & 63;
    const int w    = tid >> 6;
    const int wm   = w >> 1, wn = w & 1;
    const int m0   = blockIdx.y * 64, n0 = blockIdx.x * 64;

    f32x4 acc[2][2] = {};

    for (int k0 = 0; k0 < K; k0 += 64) {
        #pragma unroll
        for (int s = 0; s < 2; ++s) {
            int slot = tid + s * 256;          // 512 slots of 8 elems
            int row  = slot >> 3;
            int c8   = (slot & 7) * 8;
            int sw   = c8 ^ ((row & 7) << 3);
            i32x4 va = *reinterpret_cast<const i32x4*>(A  + (size_t)(m0 + row) * K + k0 + c8);
            *reinterpret_cast<i32x4*>(As + row * 64 + sw) = va;
            i32x4 vb = *reinterpret_cast<const i32x4*>(Bt + (size_t)(n0 + row) * K + k0 + c8);
            *reinterpret_cast<i32x4*>(Bs + row * 64 + sw) = vb;
        }
        __syncthreads();
        #pragma unroll
        for (int ks = 0; ks < 2; ++ks) {
            bf16x8 af[2], bfr[2];
            #pragma unroll
            for (int mi = 0; mi < 2; ++mi) {
                int row = wm * 32 + mi * 16 + (lane & 15);
                int col = (ks * 32 + ((lane >> 4) * 8)) ^ ((row & 7) << 3);
                af[mi] = *reinterpret_cast<const bf16x8*>(As + row * 64 + col);
            }
            #pragma unroll
            for (int ni = 0; ni < 2; ++ni) {
                int row = wn * 32 + ni * 16 + (lane & 15);
                int col = (ks * 32 + ((lane >> 4) * 8)) ^ ((row & 7) << 3);
                bfr[ni] = *reinterpret_cast<const bf16x8*>(Bs + row * 64 + col);
            }
            #pragma unroll
            for (int mi = 0; mi < 2; ++mi)
                #pragma unroll
                for (int ni = 0; ni < 2; ++ni)
                    acc[mi][ni] = __builtin_amdgcn_mfma_f32_16x16x32_bf16(
                        af[mi], bfr[ni], acc[mi][ni], 0, 0, 0);
        }
        __syncthreads();
    }

    #pragma unroll
    for (int mi = 0; mi < 2; ++mi)
        #pragma unroll
        for (int ni = 0; ni < 2; ++ni) {
            int col = n0 + wn * 32 + ni * 16 + (lane & 15);
            float bv = bias[col];
            #pragma unroll
            for (int i = 0; i < 4; ++i) {
                int row = m0 + wm * 32 + mi * 16 + ((lane >> 4) * 4) + i;
                store_out(&C[(size_t)row * N + col], acc[mi][ni][i] + bv);
            }
        }
}

// ---------------------------------------------------------------------------
// RoPE in-place on bf16 buffer x[rows][heads*64]; heads = 1<<hbits
// x'[d]    = x[d]*cos - x[d+32]*sin      (d < 32)
// x'[d+32] = x[d+32]*cos + x[d]*sin
// cos/sin tables: [T][64], value at d equals value at d+32 -> read d only.
// ---------------------------------------------------------------------------
__global__ __launch_bounds__(256) void rope_kernel(
    short* __restrict__ x, const float* __restrict__ cosE,
    const float* __restrict__ sinE, int hbits)
{
    int idx = blockIdx.x * 256 + threadIdx.x;   // rows*heads*32 threads
    int dp  = idx & 31;
    int hh  = (idx >> 5) & ((1 << hbits) - 1);
    int row = idx >> (5 + hbits);
    int t   = row & (Tc - 1);
    float c = cosE[t * 64 + dp];
    float s = sinE[t * 64 + dp];
    size_t base = (size_t)row * (64 << hbits) + hh * 64 + dp;
    union { short s16; __hip_bfloat16 h; } u1, u2;
    u1.s16 = x[base];
    u2.s16 = x[base + 32];
    float x1 = __bfloat162float(u1.h);
    float x2 = __bfloat162float(u2.h);
    x[base]      = f2bf_bits(x1 * c - x2 * s);
    x[base + 32] = f2bf_bits(x2 * c + x1 * s);
}

// ---------------------------------------------------------------------------
// Causal GQA flash attention.
// Block: 64 queries (one (b,h,qtile)), 4 waves x 16 rows each. KV tile = 32.
// Q in registers; K in LDS (swizzled rows); V transposed into LDS at staging;
// P routed through per-wave swizzled LDS to convert D-layout -> A-layout.
// ---------------------------------------------------------------------------
__global__ __launch_bounds__(256) void flash_gqa(
    const short* __restrict__ Q,   // [B*T][H*D]  bf16 bits (post-RoPE)
    const short* __restrict__ Kx,  // [B*T][KV*D] bf16 bits (post-RoPE)
    const short* __restrict__ Vx,  // [B*T][KV*D] bf16 bits
    __hip_bfloat16* __restrict__ O)// [B*T][H*D]
{
    constexpr float scale = 0.125f;  // 1/sqrt(64)
    __shared__ short Ks[32 * 64];    // [kv][d]  swizzled
    __shared__ short Vt[64 * 32];    // [d][kv]  swizzled
    __shared__ short Ps[4][16 * 32]; // per-wave P, swizzled

    const int tid  = threadIdx.x;
    const int lane = tid & 63;
    const int w    = tid >> 6;
    const int qt   = (int)gridDim.x - 1 - (int)blockIdx.x; // long blocks first
    const int h    = blockIdx.y;
    const int b    = blockIdx.z;
    const int q0   = qt * 64;
    const int kvh  = h >> 2;   // G = 4

    // Q fragments (A-operand), held in registers across the kv loop
    bf16x8 aq[2];
    {
        int row = b * Tc + q0 + w * 16 + (lane & 15);
        #pragma unroll
        for (int ks = 0; ks < 2; ++ks)
            aq[ks] = *reinterpret_cast<const bf16x8*>(
                Q + (size_t)row * Ec + h * 64 + ks * 32 + ((lane >> 4) * 8));
    }

    float m_i[4], l_i[4];
    f32x4 o_acc[4] = {};
    #pragma unroll
    for (int i = 0; i < 4; ++i) { m_i[i] = -1e30f; l_i[i] = 0.f; }

    const int qw_max = q0 + w * 16 + 15;
    const int kv_end = q0 + 64;

    for (int kb = 0; kb < kv_end; kb += 32) {
        // --- stage K tile [32][64] and V^T tile [64][32] ---
        {
            int row = tid >> 3;             // kv row 0..31
            int c8  = (tid & 7) * 8;        // d slot
            size_t gsrc = (size_t)(b * Tc + kb + row) * (KVc * Dc) + kvh * 64 + c8;
            i32x4 vk = *reinterpret_cast<const i32x4*>(Kx + gsrc);
            *reinterpret_cast<i32x4*>(Ks + row * 64 + (c8 ^ ((row & 7) << 3))) = vk;
            i32x4 vv = *reinterpret_cast<const i32x4*>(Vx + gsrc);
            union { i32x4 v; short s[8]; } u; u.v = vv;
            #pragma unroll
            for (int j = 0; j < 8; ++j) {
                int d = c8 + j;
                Vt[d * 32 + (row ^ ((d & 3) << 3))] = u.s[j];
            }
        }
        __syncthreads();

        if (kb <= qw_max) {
            // --- S = Q K^T (16x32) ---
            f32x4 s_acc[2] = {};
            #pragma unroll
            for (int ks = 0; ks < 2; ++ks)
                #pragma unroll
                for (int nt = 0; nt < 2; ++nt) {
                    int row = nt * 16 + (lane & 15);
                    int col = (ks * 32 + ((lane >> 4) * 8)) ^ ((row & 7) << 3);
                    bf16x8 bk = *reinterpret_cast<const bf16x8*>(Ks + row * 64 + col);
                    s_acc[nt] = __builtin_amdgcn_mfma_f32_16x16x32_bf16(
                        aq[ks], bk, s_acc[nt], 0, 0, 0);
                }

            // --- mask + online softmax (rows live in 16-lane groups) ---
            float p[2][4], rm[4], rs[4], corr[4];
            const int qi0 = q0 + w * 16 + ((lane >> 4) * 4);
            #pragma unroll
            for (int i = 0; i < 4; ++i) {
                #pragma unroll
                for (int nt = 0; nt < 2; ++nt) {
                    int kj = kb + nt * 16 + (lane & 15);
                    float s = s_acc[nt][i] * scale;
                    p[nt][i] = (kj > qi0 + i) ? -1e30f : s;
                }
                rm[i] = fmaxf(p[0][i], p[1][i]);
            }
            #pragma unroll
            for (int off = 1; off < 16; off <<= 1)
                #pragma unroll
                for (int i = 0; i < 4; ++i)
                    rm[i] = fmaxf(rm[i], __shfl_xor(rm[i], off));
            #pragma unroll
            for (int i = 0; i < 4; ++i) {
                float mn = fmaxf(m_i[i], rm[i]);
                corr[i] = __expf(m_i[i] - mn);
                m_i[i]  = mn;
                p[0][i] = __expf(p[0][i] - mn);
                p[1][i] = __expf(p[1][i] - mn);
                rs[i]   = p[0][i] + p[1][i];
            }
            #pragma unroll
            for (int off = 1; off < 16; off <<= 1)
                #pragma unroll
                for (int i = 0; i < 4; ++i)
                    rs[i] += __shfl_xor(rs[i], off);
            #pragma unroll
            for (int i = 0; i < 4; ++i)
                l_i[i] = l_i[i] * corr[i] + rs[i];
            #pragma unroll
            for (int nt = 0; nt < 4; ++nt)
                #pragma unroll
                for (int i = 0; i < 4; ++i)
                    o_acc[nt][i] *= corr[i];

            // --- P (D-layout) -> LDS -> A-layout ---
            #pragma unroll
            for (int nt = 0; nt < 2; ++nt)
                #pragma unroll
                for (int i = 0; i < 4; ++i) {
                    int row = ((lane >> 4) * 4) + i;
                    int col = nt * 16 + (lane & 15);
                    Ps[w][row * 32 + (col ^ ((row & 3) << 3))] = f2bf_bits(p[nt][i]);
                }
            int mrow = lane & 15;
            bf16x8 ap = *reinterpret_cast<const bf16x8*>(
                &Ps[w][mrow * 32 + (((lane >> 4) * 8) ^ ((mrow & 3) << 3))]);

            // --- O += P V ---
            #pragma unroll
            for (int nt = 0; nt < 4; ++nt) {
                int d = nt * 16 + (lane & 15);
                bf16x8 bv = *reinterpret_cast<const bf16x8*>(
                    &Vt[d * 32 + (((lane >> 4) * 8) ^ ((d & 3) << 3))]);
                o_acc[nt] = __builtin_amdgcn_mfma_f32_16x16x32_bf16(
                    ap, bv, o_acc[nt], 0, 0, 0);
            }
        }
        __syncthreads();
    }

    // --- epilogue: O / l ---
    #pragma unroll
    for (int nt = 0; nt < 4; ++nt)
        #pragma unroll
        for (int i = 0; i < 4; ++i) {
            int row = b * Tc + q0 + w * 16 + ((lane >> 4) * 4) + i;
            int col = h * 64 + nt * 16 + (lane & 15);
            O[(size_t)row * Ec + col] = __float2bfloat16(o_acc[nt][i] / l_i[i]);
        }
}

// ---------------------------------------------------------------------------
extern "C" void kernel_launch(void* const* d_in, const int* in_sizes, int n_in,
                              void* d_out, int out_size, void* d_ws, size_t ws_size,
                              hipStream_t stream)
{
    const float* query = (const float*)d_in[0];
    const float* key   = (const float*)d_in[1];
    const float* value = (const float*)d_in[2];
    const float* cosE  = (const float*)d_in[3];
    const float* sinE  = (const float*)d_in[4];
    // d_in[5] = mask (tril; causality is hard-coded)
    const float* Wq = (const float*)d_in[6];
    const float* bq = (const float*)d_in[7];
    const float* Wk = (const float*)d_in[8];
    const float* bk = (const float*)d_in[9];
    const float* Wv = (const float*)d_in[10];
    const float* bv = (const float*)d_in[11];
    const float* Wo = (const float*)d_in[12];
    const float* bo = (const float*)d_in[13];

    const int M  = Bc * Tc;      // 4096
    const int NK = KVc * Dc;     // 256

    char* ws = (char*)d_ws;
    size_t off = 0;
    auto alloc = [&](size_t bytes) { char* p = ws + off; off += bytes; return p; };

    short* Xq   = (short*)alloc((size_t)M * Ec * 2);
    short* Xk   = (short*)alloc((size_t)M * Ec * 2);
    short* Xv   = (short*)alloc((size_t)M * Ec * 2);
    short* Wqt  = (short*)alloc((size_t)Ec * Ec * 2);
    short* Wkt  = (short*)alloc((size_t)NK * Ec * 2);
    short* Wvt  = (short*)alloc((size_t)NK * Ec * 2);
    short* Wot  = (short*)alloc((size_t)Ec * Ec * 2);
    short* Qp   = (short*)alloc((size_t)M * Ec * 2);
    short* Kp   = (short*)alloc((size_t)M * NK * 2);
    short* Vp   = (short*)alloc((size_t)M * NK * 2);
    short* attn = (short*)alloc((size_t)M * Ec * 2);
    (void)ws_size; // total ~49 MB

    const int nX = M * Ec;   // 4194304
    conv_f32_bf16<<<nX / 4 / 256, 256, 0, stream>>>(query, Xq, nX);
    conv_f32_bf16<<<nX / 4 / 256, 256, 0, stream>>>(key,   Xk, nX);
    conv_f32_bf16<<<nX / 4 / 256, 256, 0, stream>>>(value, Xv, nX);

    transp_conv<<<dim3(Ec / 32, Ec / 32), 256, 0, stream>>>(Wq, Wqt, Ec, Ec);
    transp_conv<<<dim3(NK / 32, Ec / 32), 256, 0, stream>>>(Wk, Wkt, Ec, NK);
    transp_conv<<<dim3(NK / 32, Ec / 32), 256, 0, stream>>>(Wv, Wvt, Ec, NK);
    transp_conv<<<dim3(Ec / 32, Ec / 32), 256, 0, stream>>>(Wo, Wot, Ec, Ec);

    gemm_bf16_nt<short><<<dim3(Ec / 64, M / 64), 256, 0, stream>>>(Xq, Wqt, bq, Qp, M, Ec, Ec);
    gemm_bf16_nt<short><<<dim3(NK / 64, M / 64), 256, 0, stream>>>(Xk, Wkt, bk, Kp, M, NK, Ec);
    gemm_bf16_nt<short><<<dim3(NK / 64, M / 64), 256, 0, stream>>>(Xv, Wvt, bv, Vp, M, NK, Ec);

    rope_kernel<<<(M * Hc  * 32) / 256, 256, 0, stream>>>(Qp, cosE, sinE, 4); // 16 heads
    rope_kernel<<<(M * KVc * 32) / 256, 256, 0, stream>>>(Kp, cosE, sinE, 2); // 4 heads

    flash_gqa<<<dim3(Tc / 64, Hc, Bc), 256, 0, stream>>>(Qp, Kp, Vp, (__hip_bfloat16*)attn);

    gemm_bf16_nt<float><<<dim3(Ec / 64, M / 64), 256, 0, stream>>>(
        attn, Wot, bo, (float*)d_out, M, Ec, Ec);
}

// Round 2
// 212.880 us; speedup vs baseline: 1.4296x; 1.4296x over previous
//
#include <hip/hip_runtime.h>
#include <hip/hip_bf16.h>

// Problem constants
constexpr int Bc  = 2;
constexpr int Tc  = 2048;
constexpr int Ec  = 1024;
constexpr int Hc  = 16;
constexpr int KVc = 4;
constexpr int Dc  = 64;
// G = Hc/KVc = 4

typedef short bf16x8 __attribute__((ext_vector_type(8)));
typedef float f32x4  __attribute__((ext_vector_type(4)));
typedef float f32x16 __attribute__((ext_vector_type(16)));
typedef int   i32x4  __attribute__((ext_vector_type(4)));

__device__ inline short f2bf_bits(float f) {
    union { __hip_bfloat16 h; short s; } u;
    u.h = __float2bfloat16(f);
    return u.s;
}

__device__ inline unsigned pkbf(float a, float b) {
    return (unsigned)(unsigned short)f2bf_bits(a)
         | ((unsigned)(unsigned short)f2bf_bits(b) << 16);
}

// ---------------------------------------------------------------------------
// fp32 -> bf16 elementwise convert (vectorized)
// ---------------------------------------------------------------------------
__global__ __launch_bounds__(256) void conv_f32_bf16(
    const float* __restrict__ x, short* __restrict__ y, int n)
{
    int i = (blockIdx.x * 256 + threadIdx.x) * 4;
    if (i >= n) return;
    float4 v = *reinterpret_cast<const float4*>(x + i);
    typedef short short4v __attribute__((ext_vector_type(4)));
    short4v o;
    o[0] = f2bf_bits(v.x);
    o[1] = f2bf_bits(v.y);
    o[2] = f2bf_bits(v.z);
    o[3] = f2bf_bits(v.w);
    *reinterpret_cast<short4v*>(y + i) = o;
}

// ---------------------------------------------------------------------------
// transpose + convert: W[K][N] fp32 -> Wt[N][K] bf16
// ---------------------------------------------------------------------------
__global__ __launch_bounds__(256) void transp_conv(
    const float* __restrict__ W, short* __restrict__ Wt, int K, int N)
{
    __shared__ float tile[32][33];
    int nb = blockIdx.x * 32, kb = blockIdx.y * 32;
    int tx = threadIdx.x & 31, ty = threadIdx.x >> 5;   // ty 0..7
    #pragma unroll
    for (int j = 0; j < 4; ++j)
        tile[ty + j * 8][tx] = W[(size_t)(kb + ty + j * 8) * N + nb + tx];
    __syncthreads();
    #pragma unroll
    for (int j = 0; j < 4; ++j)
        Wt[(size_t)(nb + ty + j * 8) * K + kb + tx] = f2bf_bits(tile[tx][ty + j * 8]);
}

// ---------------------------------------------------------------------------
// bf16 MFMA GEMM: C[M][N] = A[M][K] @ Bt[N][K]^T + bias
// 64x64 tile, BK=64, 4 waves (2x2), each wave 32x32.
// TRANSV: store output transposed as VT[(row>>11)*256 + col][row&2047] (bf16).
// ---------------------------------------------------------------------------
__device__ inline void store_out(short* p, float v)  { *p = f2bf_bits(v); }
__device__ inline void store_out(float* p, float v)  { *p = v; }

template<typename OutT, bool TRANSV>
__global__ __launch_bounds__(256) void gemm_bf16_nt(
    const short* __restrict__ A,   // [M][K] bf16 bits
    const short* __restrict__ Bt,  // [N][K] bf16 bits
    const float* __restrict__ bias,// [N]
    OutT* __restrict__ C,
    int M, int N, int K)
{
    __shared__ short As[64 * 64];
    __shared__ short Bs[64 * 64];
    const int tid  = threadIdx.x;
    const int lane = tid & 63;
    const int w    = tid >> 6;
    const int wm   = w >> 1, wn = w & 1;
    const int m0   = blockIdx.y * 64, n0 = blockIdx.x * 64;

    f32x4 acc[2][2] = {};

    for (int k0 = 0; k0 < K; k0 += 64) {
        #pragma unroll
        for (int s = 0; s < 2; ++s) {
            int slot = tid + s * 256;          // 512 slots of 8 elems
            int row  = slot >> 3;
            int c8   = (slot & 7) * 8;
            int sw   = c8 ^ ((row & 7) << 3);
            i32x4 va = *reinterpret_cast<const i32x4*>(A  + (size_t)(m0 + row) * K + k0 + c8);
            *reinterpret_cast<i32x4*>(As + row * 64 + sw) = va;
            i32x4 vb = *reinterpret_cast<const i32x4*>(Bt + (size_t)(n0 + row) * K + k0 + c8);
            *reinterpret_cast<i32x4*>(Bs + row * 64 + sw) = vb;
        }
        __syncthreads();
        #pragma unroll
        for (int ks = 0; ks < 2; ++ks) {
            bf16x8 af[2], bfr[2];
            #pragma unroll
            for (int mi = 0; mi < 2; ++mi) {
                int row = wm * 32 + mi * 16 + (lane & 15);
                int col = (ks * 32 + ((lane >> 4) * 8)) ^ ((row & 7) << 3);
                af[mi] = *reinterpret_cast<const bf16x8*>(As + row * 64 + col);
            }
            #pragma unroll
            for (int ni = 0; ni < 2; ++ni) {
                int row = wn * 32 + ni * 16 + (lane & 15);
                int col = (ks * 32 + ((lane >> 4) * 8)) ^ ((row & 7) << 3);
                bfr[ni] = *reinterpret_cast<const bf16x8*>(Bs + row * 64 + col);
            }
            #pragma unroll
            for (int mi = 0; mi < 2; ++mi)
                #pragma unroll
                for (int ni = 0; ni < 2; ++ni)
                    acc[mi][ni] = __builtin_amdgcn_mfma_f32_16x16x32_bf16(
                        af[mi], bfr[ni], acc[mi][ni], 0, 0, 0);
        }
        __syncthreads();
    }

    #pragma unroll
    for (int mi = 0; mi < 2; ++mi)
        #pragma unroll
        for (int ni = 0; ni < 2; ++ni) {
            int col = n0 + wn * 32 + ni * 16 + (lane & 15);
            float bv = bias[col];
            #pragma unroll
            for (int i = 0; i < 4; ++i) {
                int row = m0 + wm * 32 + mi * 16 + ((lane >> 4) * 4) + i;
                float v = acc[mi][ni][i] + bv;
                if constexpr (TRANSV) {
                    // V^T: [(b*256 + col)][t], b = row>>11, t = row&2047
                    ((short*)C)[(((size_t)(row >> 11) * 256 + col) << 11) + (row & 2047)]
                        = f2bf_bits(v);
                } else {
                    store_out(&C[(size_t)row * N + col], v);
                }
            }
        }
}

// ---------------------------------------------------------------------------
// RoPE in-place on bf16 buffer x[rows][heads*64]; heads = 1<<hbits.
// Also multiplies by `scale` (used to fold 1/sqrt(D) into Q).
// ---------------------------------------------------------------------------
__global__ __launch_bounds__(256) void rope_kernel(
    short* __restrict__ x, const float* __restrict__ cosE,
    const float* __restrict__ sinE, int hbits, float scale)
{
    int idx = blockIdx.x * 256 + threadIdx.x;   // rows*heads*32 threads
    int dp  = idx & 31;
    int hh  = (idx >> 5) & ((1 << hbits) - 1);
    int row = idx >> (5 + hbits);
    int t   = row & (Tc - 1);
    float c = cosE[t * 64 + dp];
    float s = sinE[t * 64 + dp];
    size_t base = (size_t)row * (64 << hbits) + hh * 64 + dp;
    union { short s16; __hip_bfloat16 h; } u1, u2;
    u1.s16 = x[base];
    u2.s16 = x[base + 32];
    float x1 = __bfloat162float(u1.h);
    float x2 = __bfloat162float(u2.h);
    x[base]      = f2bf_bits((x1 * c - x2 * s) * scale);
    x[base + 32] = f2bf_bits((x2 * c + x1 * s) * scale);
}

// ---------------------------------------------------------------------------
// Causal GQA flash attention, swapped-QK^T, zero barriers in kv loop.
// Block = 4 independent waves; wave owns 32 q-rows; KVBLK = 64.
// S^T = mfma(A=K, B=Q)  -> lane owns q-column (lane&31): softmax lane-local.
// O^T = mfma(A=V^T, B=P) -> same q-column ownership; stats stay scalar.
// K from global rows; V^T pre-materialized by the V-projection GEMM.
// LDS only for the transposed epilogue (coalesced stores).
// ---------------------------------------------------------------------------
__global__ __launch_bounds__(256) void flash_gqa2(
    const short* __restrict__ Q,   // [B*T][H*D] bf16, post-RoPE, pre-scaled
    const short* __restrict__ Kx,  // [B*T][KV*D] bf16, post-RoPE
    const short* __restrict__ VT,  // [B*KV][D][T] bf16
    short* __restrict__ O)         // [B*T][H*D] bf16
{
    __shared__ short obuf[4][32 * 64];
    const int lane = threadIdx.x & 63;
    const int w    = threadIdx.x >> 6;
    const int lo   = lane & 31;
    const int hi   = lane >> 5;

    // XCD-grouped decode: 4 q-heads of one KV head per XCD; long qt first.
    const int L     = blockIdx.x;          // 0..511
    const int i     = L >> 3;              // 0..63
    const int combo = (L & 7) * 4 + (i >> 4);
    const int h     = combo & 15;
    const int b     = combo >> 4;
    const int qt    = 15 - (i & 15);
    const int kvh   = h >> 2;

    const int q0w = qt * 128 + w * 32;     // this wave's q-tile base
    const int qg  = q0w + lo;              // this lane's q column

    // Q B-fragments (4 k-slices of d), held across the loop
    bf16x8 qf[4];
    {
        const short* qp = Q + (size_t)(b * Tc + qg) * Ec + h * 64 + hi * 8;
        #pragma unroll
        for (int ds = 0; ds < 4; ++ds)
            qf[ds] = *reinterpret_cast<const bf16x8*>(qp + 16 * ds);
    }
    const short* Kb = Kx + (size_t)b * Tc * (KVc * Dc) + kvh * 64;
    const short* Vb = VT + (size_t)(b * KVc + kvh) * 64 * Tc;

    float m = -1e30f, l = 0.f;
    f32x16 o0 = {}, o1 = {};

    const int kv_hi = q0w + 32;
    for (int kb = 0; kb < kv_hi; kb += 64) {
        // --- load K fragments (A-op: [kk][d]) and V^T fragments (A-op: [d][kk])
        bf16x8 kf[2][4], vf[2][4];
        #pragma unroll
        for (int t = 0; t < 2; ++t)
            #pragma unroll
            for (int ds = 0; ds < 4; ++ds)
                kf[t][ds] = *reinterpret_cast<const bf16x8*>(
                    Kb + (size_t)(kb + 32 * t + lo) * (KVc * Dc) + 16 * ds + 8 * hi);
        #pragma unroll
        for (int td = 0; td < 2; ++td)
            #pragma unroll
            for (int sl = 0; sl < 4; ++sl)
                vf[td][sl] = *reinterpret_cast<const bf16x8*>(
                    Vb + (size_t)(32 * td + lo) * Tc + kb + 16 * sl + 8 * hi);

        // --- S^T[kk][q] = K Q^T ---
        f32x16 s0 = {}, s1 = {};
        #pragma unroll
        for (int ds = 0; ds < 4; ++ds) {
            s0 = __builtin_amdgcn_mfma_f32_32x32x16_bf16(kf[0][ds], qf[ds], s0, 0, 0, 0);
            s1 = __builtin_amdgcn_mfma_f32_32x32x16_bf16(kf[1][ds], qf[ds], s1, 0, 0, 0);
        }

        // --- causal mask (wave-uniform branch: only the diagonal iteration) ---
        if (kb + 63 > q0w) {
            #pragma unroll
            for (int r = 0; r < 16; ++r) {
                int kkl = (r & 3) + 8 * (r >> 2) + 4 * hi;
                if (kb + kkl > qg)      s0[r] = -1e30f;
                if (kb + 32 + kkl > qg) s1[r] = -1e30f;
            }
        }

        // --- online softmax: lane-local + one cross-half exchange ---
        float pm = fmaxf(s0[0], s1[0]);
        #pragma unroll
        for (int r = 1; r < 16; ++r) pm = fmaxf(pm, fmaxf(s0[r], s1[r]));
        pm = fmaxf(pm, __shfl_xor(pm, 32));
        float mn   = fmaxf(m, pm);
        float corr = __expf(m - mn);
        m = mn;
        float rs = 0.f;
        #pragma unroll
        for (int r = 0; r < 16; ++r) {
            s0[r] = __expf(s0[r] - m);
            s1[r] = __expf(s1[r] - m);
            rs += s0[r] + s1[r];
        }
        rs += __shfl_xor(rs, 32);
        l = l * corr + rs;
        #pragma unroll
        for (int r = 0; r < 16; ++r) { o0[r] *= corr; o1[r] *= corr; }

        // --- pack P into B-fragments (kk-slices of 16) and PV ---
        #pragma unroll
        for (int t = 0; t < 2; ++t) {
            f32x16 sv = t ? s1 : s0;
            unsigned wv[8], sx[8];
            #pragma unroll
            for (int j = 0; j < 8; ++j) wv[j] = pkbf(sv[2 * j], sv[2 * j + 1]);
            #pragma unroll
            for (int j = 0; j < 8; ++j) sx[j] = __shfl_xor(wv[j], 32);
            #pragma unroll
            for (int u = 0; u < 2; ++u) {
                union { unsigned u4[4]; bf16x8 v; } pf;
                pf.u4[0] = hi ? sx[4 * u + 2] : wv[4 * u];
                pf.u4[1] = hi ? sx[4 * u + 3] : wv[4 * u + 1];
                pf.u4[2] = hi ? wv[4 * u + 2] : sx[4 * u];
                pf.u4[3] = hi ? wv[4 * u + 3] : sx[4 * u + 1];
                int sl = 2 * t + u;
                o0 = __builtin_amdgcn_mfma_f32_32x32x16_bf16(vf[0][sl], pf.v, o0, 0, 0, 0);
                o1 = __builtin_amdgcn_mfma_f32_32x32x16_bf16(vf[1][sl], pf.v, o1, 0, 0, 0);
            }
        }
    }

    // --- epilogue: O^T/l -> LDS transpose -> coalesced global stores ---
    float inv = 1.0f / l;
    short* ob = obuf[w];
    #pragma unroll
    for (int r = 0; r < 16; ++r) {
        int d0 = (r & 3) + 8 * (r >> 2) + 4 * hi;
        ob[lo * 64 + ( d0        ^ ((lo & 7) << 3))] = f2bf_bits(o0[r] * inv);
        ob[lo * 64 + ((d0 + 32)  ^ ((lo & 7) << 3))] = f2bf_bits(o1[r] * inv);
    }
    // same-wave LDS read-after-write: compiler inserts lgkmcnt wait
    #pragma unroll
    for (int j = 0; j < 4; ++j) {
        int row = lane >> 1;
        int c8  = ((lane & 1) * 4 + j) * 8;
        bf16x8 v = *reinterpret_cast<const bf16x8*>(
            ob + row * 64 + (c8 ^ ((row & 7) << 3)));
        *reinterpret_cast<bf16x8*>(
            O + (size_t)(b * Tc + q0w + row) * Ec + h * 64 + c8) = v;
    }
}

// ---------------------------------------------------------------------------
extern "C" void kernel_launch(void* const* d_in, const int* in_sizes, int n_in,
                              void* d_out, int out_size, void* d_ws, size_t ws_size,
                              hipStream_t stream)
{
    const float* query = (const float*)d_in[0];
    const float* key   = (const float*)d_in[1];
    const float* value = (const float*)d_in[2];
    const float* cosE  = (const float*)d_in[3];
    const float* sinE  = (const float*)d_in[4];
    // d_in[5] = mask (tril; causality is hard-coded)
    const float* Wq = (const float*)d_in[6];
    const float* bq = (const float*)d_in[7];
    const float* Wk = (const float*)d_in[8];
    const float* bk = (const float*)d_in[9];
    const float* Wv = (const float*)d_in[10];
    const float* bv = (const float*)d_in[11];
    const float* Wo = (const float*)d_in[12];
    const float* bo = (const float*)d_in[13];

    const int M  = Bc * Tc;      // 4096
    const int NK = KVc * Dc;     // 256

    char* ws = (char*)d_ws;
    size_t off = 0;
    auto alloc = [&](size_t bytes) { char* p = ws + off; off += bytes; return p; };

    short* Xq   = (short*)alloc((size_t)M * Ec * 2);
    short* Xk   = (short*)alloc((size_t)M * Ec * 2);
    short* Xv   = (short*)alloc((size_t)M * Ec * 2);
    short* Wqt  = (short*)alloc((size_t)Ec * Ec * 2);
    short* Wkt  = (short*)alloc((size_t)NK * Ec * 2);
    short* Wvt  = (short*)alloc((size_t)NK * Ec * 2);
    short* Wot  = (short*)alloc((size_t)Ec * Ec * 2);
    short* Qp   = (short*)alloc((size_t)M * Ec * 2);
    short* Kp   = (short*)alloc((size_t)M * NK * 2);
    short* VTp  = (short*)alloc((size_t)M * NK * 2);   // [B*KV][64][T]
    short* attn = (short*)alloc((size_t)M * Ec * 2);
    (void)ws_size; // total ~49 MB

    const int nX = M * Ec;   // 4194304
    conv_f32_bf16<<<nX / 4 / 256, 256, 0, stream>>>(query, Xq, nX);
    conv_f32_bf16<<<nX / 4 / 256, 256, 0, stream>>>(key,   Xk, nX);
    conv_f32_bf16<<<nX / 4 / 256, 256, 0, stream>>>(value, Xv, nX);

    transp_conv<<<dim3(Ec / 32, Ec / 32), 256, 0, stream>>>(Wq, Wqt, Ec, Ec);
    transp_conv<<<dim3(NK / 32, Ec / 32), 256, 0, stream>>>(Wk, Wkt, Ec, NK);
    transp_conv<<<dim3(NK / 32, Ec / 32), 256, 0, stream>>>(Wv, Wvt, Ec, NK);
    transp_conv<<<dim3(Ec / 32, Ec / 32), 256, 0, stream>>>(Wo, Wot, Ec, Ec);

    gemm_bf16_nt<short, false><<<dim3(Ec / 64, M / 64), 256, 0, stream>>>(Xq, Wqt, bq, Qp,  M, Ec, Ec);
    gemm_bf16_nt<short, false><<<dim3(NK / 64, M / 64), 256, 0, stream>>>(Xk, Wkt, bk, Kp,  M, NK, Ec);
    gemm_bf16_nt<short, true ><<<dim3(NK / 64, M / 64), 256, 0, stream>>>(Xv, Wvt, bv, VTp, M, NK, Ec);

    rope_kernel<<<(M * Hc  * 32) / 256, 256, 0, stream>>>(Qp, cosE, sinE, 4, 0.125f); // Q: fold 1/sqrt(D)
    rope_kernel<<<(M * KVc * 32) / 256, 256, 0, stream>>>(Kp, cosE, sinE, 2, 1.0f);

    flash_gqa2<<<512, 256, 0, stream>>>(Qp, Kp, VTp, attn);

    gemm_bf16_nt<float, false><<<dim3(Ec / 64, M / 64), 256, 0, stream>>>(
        attn, Wot, bo, (float*)d_out, M, Ec, Ec);
}

// Round 3
// 148.531 us; speedup vs baseline: 2.0489x; 1.4332x over previous
//
#include <hip/hip_runtime.h>
#include <hip/hip_bf16.h>

// Problem constants
constexpr int Bc  = 2;
constexpr int Tc  = 2048;
constexpr int Ec  = 1024;
constexpr int Hc  = 16;
constexpr int KVc = 4;
constexpr int Dc  = 64;
// G = Hc/KVc = 4

typedef short bf16x8 __attribute__((ext_vector_type(8)));
typedef float f32x4  __attribute__((ext_vector_type(4)));
typedef float f32x16 __attribute__((ext_vector_type(16)));
typedef int   i32x4  __attribute__((ext_vector_type(4)));

__device__ inline short f2bf_bits(float f) {
    union { __hip_bfloat16 h; short s; } u;
    u.h = __float2bfloat16(f);
    return u.s;
}

__device__ inline unsigned pkbf(float a, float b) {
    return (unsigned)(unsigned short)f2bf_bits(a)
         | ((unsigned)(unsigned short)f2bf_bits(b) << 16);
}

__device__ inline float fexp2(float x) {
#if __has_builtin(__builtin_amdgcn_exp2f)
    return __builtin_amdgcn_exp2f(x);
#else
    return exp2f(x);
#endif
}

// global -> LDS async copy, 16B per lane. LDS dest must be wave-uniform base;
// HW writes base + lane*16. Global src is per-lane (pre-swizzled).
__device__ inline void gload16(const short* g, short* lds) {
    __builtin_amdgcn_global_load_lds(
        (const __attribute__((address_space(1))) unsigned int*)g,
        (__attribute__((address_space(3))) unsigned int*)lds,
        16, 0, 0);
}

// ---------------------------------------------------------------------------
// fp32 -> bf16 elementwise convert (vectorized)
// ---------------------------------------------------------------------------
__global__ __launch_bounds__(256) void conv_f32_bf16(
    const float* __restrict__ x, short* __restrict__ y, int n)
{
    int i = (blockIdx.x * 256 + threadIdx.x) * 4;
    if (i >= n) return;
    float4 v = *reinterpret_cast<const float4*>(x + i);
    typedef short short4v __attribute__((ext_vector_type(4)));
    short4v o;
    o[0] = f2bf_bits(v.x);
    o[1] = f2bf_bits(v.y);
    o[2] = f2bf_bits(v.z);
    o[3] = f2bf_bits(v.w);
    *reinterpret_cast<short4v*>(y + i) = o;
}

// ---------------------------------------------------------------------------
// transpose + convert: W[K][N] fp32 -> Wt[N][K] bf16
// ---------------------------------------------------------------------------
__global__ __launch_bounds__(256) void transp_conv(
    const float* __restrict__ W, short* __restrict__ Wt, int K, int N)
{
    __shared__ float tile[32][33];
    int nb = blockIdx.x * 32, kb = blockIdx.y * 32;
    int tx = threadIdx.x & 31, ty = threadIdx.x >> 5;   // ty 0..7
    #pragma unroll
    for (int j = 0; j < 4; ++j)
        tile[ty + j * 8][tx] = W[(size_t)(kb + ty + j * 8) * N + nb + tx];
    __syncthreads();
    #pragma unroll
    for (int j = 0; j < 4; ++j)
        Wt[(size_t)(nb + ty + j * 8) * K + kb + tx] = f2bf_bits(tile[tx][ty + j * 8]);
}

// ---------------------------------------------------------------------------
// bf16 MFMA GEMM: C[M][N] = A[M][K] @ Bt[N][K]^T + bias
// 64x64 tile, BK=64, 4 waves (2x2), each wave 32x32.
// Staging via global_load_lds w16: linear LDS dest, source pre-swizzled with
// s^(row&7) on 16B slots (rule #21: both-sides-or-neither).
// ---------------------------------------------------------------------------
__device__ inline void store_out(short* p, float v)  { *p = f2bf_bits(v); }
__device__ inline void store_out(float* p, float v)  { *p = v; }

template<typename OutT, bool TRANSV>
__global__ __launch_bounds__(256) void gemm_bf16_nt(
    const short* __restrict__ A,   // [M][K] bf16 bits
    const short* __restrict__ Bt,  // [N][K] bf16 bits
    const float* __restrict__ bias,// [N]
    OutT* __restrict__ C,
    int M, int N, int K)
{
    __shared__ short As[64 * 64];
    __shared__ short Bs[64 * 64];
    const int tid  = threadIdx.x;
    const int lane = tid & 63;
    const int w    = tid >> 6;
    const int wm   = w >> 1, wn = w & 1;
    const int m0   = blockIdx.y * 64, n0 = blockIdx.x * 64;

    const int rin = lane >> 3;          // row within 8-row chunk
    const int swc = ((lane & 7) ^ rin) * 8;  // pre-swizzled source column (shorts)

    f32x4 acc[2][2] = {};

    for (int k0 = 0; k0 < K; k0 += 64) {
        #pragma unroll
        for (int i2 = 0; i2 < 2; ++i2) {
            const int row = w * 16 + i2 * 8;            // wave-uniform
            gload16(A  + (size_t)(m0 + row + rin) * K + k0 + swc, As + row * 64);
            gload16(Bt + (size_t)(n0 + row + rin) * K + k0 + swc, Bs + row * 64);
        }
        __syncthreads();   // compiler drains vmcnt(0) before s_barrier (m97 structure)
        #pragma unroll
        for (int ks = 0; ks < 2; ++ks) {
            bf16x8 af[2], bfr[2];
            #pragma unroll
            for (int mi = 0; mi < 2; ++mi) {
                int row = wm * 32 + mi * 16 + (lane & 15);
                int col = (ks * 32 + ((lane >> 4) * 8)) ^ ((row & 7) << 3);
                af[mi] = *reinterpret_cast<const bf16x8*>(As + row * 64 + col);
            }
            #pragma unroll
            for (int ni = 0; ni < 2; ++ni) {
                int row = wn * 32 + ni * 16 + (lane & 15);
                int col = (ks * 32 + ((lane >> 4) * 8)) ^ ((row & 7) << 3);
                bfr[ni] = *reinterpret_cast<const bf16x8*>(Bs + row * 64 + col);
            }
            #pragma unroll
            for (int mi = 0; mi < 2; ++mi)
                #pragma unroll
                for (int ni = 0; ni < 2; ++ni)
                    acc[mi][ni] = __builtin_amdgcn_mfma_f32_16x16x32_bf16(
                        af[mi], bfr[ni], acc[mi][ni], 0, 0, 0);
        }
        __syncthreads();
    }

    #pragma unroll
    for (int mi = 0; mi < 2; ++mi)
        #pragma unroll
        for (int ni = 0; ni < 2; ++ni) {
            int col = n0 + wn * 32 + ni * 16 + (lane & 15);
            float bv = bias[col];
            #pragma unroll
            for (int i = 0; i < 4; ++i) {
                int row = m0 + wm * 32 + mi * 16 + ((lane >> 4) * 4) + i;
                float v = acc[mi][ni][i] + bv;
                if constexpr (TRANSV) {
                    // V^T: [(b*256 + col)][t], b = row>>11, t = row&2047
                    ((short*)C)[(((size_t)(row >> 11) * 256 + col) << 11) + (row & 2047)]
                        = f2bf_bits(v);
                } else {
                    store_out(&C[(size_t)row * N + col], v);
                }
            }
        }
}

// ---------------------------------------------------------------------------
// RoPE in-place on bf16 buffer x[rows][heads*64]; heads = 1<<hbits.
// Also multiplies by `scale` (Q: 1/sqrt(D) * log2(e) for exp2-domain softmax).
// ---------------------------------------------------------------------------
__global__ __launch_bounds__(256) void rope_kernel(
    short* __restrict__ x, const float* __restrict__ cosE,
    const float* __restrict__ sinE, int hbits, float scale)
{
    int idx = blockIdx.x * 256 + threadIdx.x;   // rows*heads*32 threads
    int dp  = idx & 31;
    int hh  = (idx >> 5) & ((1 << hbits) - 1);
    int row = idx >> (5 + hbits);
    int t   = row & (Tc - 1);
    float c = cosE[t * 64 + dp];
    float s = sinE[t * 64 + dp];
    size_t base = (size_t)row * (64 << hbits) + hh * 64 + dp;
    union { short s16; __hip_bfloat16 h; } u1, u2;
    u1.s16 = x[base];
    u2.s16 = x[base + 32];
    float x1 = __bfloat162float(u1.h);
    float x2 = __bfloat162float(u2.h);
    x[base]      = f2bf_bits((x1 * c - x2 * s) * scale);
    x[base + 32] = f2bf_bits((x2 * c + x1 * s) * scale);
}

// ---------------------------------------------------------------------------
// Causal GQA flash attention v3.
// Block = 4 waves, wave owns 32 q-rows; KVBLK = 64; LDS-staged K/V tiles,
// double-buffered via global_load_lds + counted vmcnt + raw barriers.
// S^T = mfma(A=K, B=Q); O^T = mfma(A=V^T, B=P); softmax lane-local, exp2
// domain (Q pre-scaled by 1/sqrt(D)*log2e), defer-max rescale (T13).
// ---------------------------------------------------------------------------
__global__ __launch_bounds__(256) void flash_gqa3(
    const short* __restrict__ Q,   // [B*T][H*D] bf16, post-RoPE, pre-scaled
    const short* __restrict__ Kx,  // [B*T][KV*D] bf16, post-RoPE
    const short* __restrict__ VT,  // [B*KV][D][T] bf16
    short* __restrict__ O)         // [B*T][H*D] bf16
{
    __shared__ short Kbuf[2][64 * 64];  // [kv][d] swizzled, 2 x 8KB
    __shared__ short Vbuf[2][64 * 64];  // [d][kv] swizzled, 2 x 8KB
    __shared__ short obuf[4][32 * 64];  // epilogue transpose

    const int lane = threadIdx.x & 63;
    const int w    = threadIdx.x >> 6;
    const int lo   = lane & 31;
    const int hi   = lane >> 5;

    // Decode: XCD x (=L&7) owns combos 4x..4x+3 (one kvh per XCD).
    // qt(L) + qt(L+256) = 15 so each CU's two resident blocks balance.
    const int L  = blockIdx.x;              // 0..511
    const int ii = L >> 3;                  // 0..63
    const int cs = (ii >> 4) & 3;
    const int combo = (L & 7) * 4 + cs;
    const int h  = combo & 15;
    const int b  = combo >> 4;
    const int qt = ((ii >> 5) & 1) ? (ii & 15) : 15 - (ii & 15);
    const int kvh = h >> 2;

    const int q0w = qt * 128 + w * 32;      // this wave's q-tile base
    const int qg  = q0w + lo;               // this lane's q column

    // Q B-fragments (4 k-slices of d), held across the loop
    bf16x8 qf[4];
    {
        const short* qp = Q + (size_t)(b * Tc + qg) * Ec + h * 64 + hi * 8;
        #pragma unroll
        for (int ds = 0; ds < 4; ++ds)
            qf[ds] = *reinterpret_cast<const bf16x8*>(qp + 16 * ds);
    }
    const short* Kb = Kx + (size_t)b * Tc * (KVc * Dc) + kvh * 64;
    const short* Vb = VT + (size_t)(b * KVc + kvh) * 64 * Tc;

    // wave w stages K rows 16w..16w+15 and V^T rows 16w..16w+15 (4 gload_lds)
    const int rin = lane >> 3;
    const int swc = ((lane & 7) ^ rin) * 8;
    auto stage = [&](int bufi, int kb2) {
        #pragma unroll
        for (int i2 = 0; i2 < 2; ++i2) {
            const int row = w * 16 + i2 * 8;       // wave-uniform LDS base row
            gload16(Kb + (size_t)(kb2 + row + rin) * 256 + swc,
                    &Kbuf[bufi][row * 64]);
            gload16(Vb + (size_t)(row + rin) * Tc + kb2 + swc,
                    &Vbuf[bufi][row * 64]);
        }
    };

    const int nt = qt * 2 + 2;              // kv tiles this block
    stage(0, 0);

    float m = -1e30f, l = 0.f;
    f32x16 o0 = {}, o1 = {};
    const int kv_hi = q0w + 32;

    for (int t = 0; t < nt; ++t) {
        const int kb  = t * 64;
        const int cur = t & 1;
        if (t + 1 < nt) {
            stage(cur ^ 1, kb + 64);
            asm volatile("s_waitcnt vmcnt(4)" ::: "memory");  // tile t landed
        } else {
            asm volatile("s_waitcnt vmcnt(0)" ::: "memory");
        }
        __builtin_amdgcn_s_barrier();

        if (kb < kv_hi) {
            const short* Kl = Kbuf[cur];
            const short* Vl = Vbuf[cur];
            bf16x8 kf[2][4], vf[2][4];
            #pragma unroll
            for (int t2 = 0; t2 < 2; ++t2)
                #pragma unroll
                for (int ds = 0; ds < 4; ++ds) {
                    int row = 32 * t2 + lo;
                    int sl  = (2 * ds + hi) ^ (lo & 7);
                    kf[t2][ds] = *reinterpret_cast<const bf16x8*>(Kl + row * 64 + sl * 8);
                }
            #pragma unroll
            for (int td = 0; td < 2; ++td)
                #pragma unroll
                for (int sl2 = 0; sl2 < 4; ++sl2) {
                    int row = 32 * td + lo;
                    int sl  = (2 * sl2 + hi) ^ (lo & 7);
                    vf[td][sl2] = *reinterpret_cast<const bf16x8*>(Vl + row * 64 + sl * 8);
                }

            // --- S^T[kk][q] = K Q^T ---
            f32x16 s0 = {}, s1 = {};
            #pragma unroll
            for (int ds = 0; ds < 4; ++ds) {
                s0 = __builtin_amdgcn_mfma_f32_32x32x16_bf16(kf[0][ds], qf[ds], s0, 0, 0, 0);
                s1 = __builtin_amdgcn_mfma_f32_32x32x16_bf16(kf[1][ds], qf[ds], s1, 0, 0, 0);
            }

            // --- causal mask (only the diagonal iterations) ---
            if (kb + 63 > q0w) {
                #pragma unroll
                for (int r = 0; r < 16; ++r) {
                    int kkl = (r & 3) + 8 * (r >> 2) + 4 * hi;
                    if (kb + kkl > qg)      s0[r] = -1e30f;
                    if (kb + 32 + kkl > qg) s1[r] = -1e30f;
                }
            }

            // --- online softmax: tree max, defer-max rescale, exp2 ---
            float mx[8];
            #pragma unroll
            for (int j = 0; j < 8; ++j)
                mx[j] = fmaxf(fmaxf(s0[2 * j], s0[2 * j + 1]),
                              fmaxf(s1[2 * j], s1[2 * j + 1]));
            #pragma unroll
            for (int st = 4; st > 0; st >>= 1)
                #pragma unroll
                for (int j = 0; j < st; ++j) mx[j] = fmaxf(mx[j], mx[j + st]);
            float pm = fmaxf(mx[0], __shfl_xor(mx[0], 32));

            float corr = 1.0f;
            if (__any(pm > m + 8.0f)) {       // T13: rescale only on real growth
                float mn = fmaxf(m, pm);
                corr = fexp2(m - mn);
                m = mn;
                #pragma unroll
                for (int r = 0; r < 16; ++r) { o0[r] *= corr; o1[r] *= corr; }
            }
            float rs = 0.f;
            #pragma unroll
            for (int r = 0; r < 16; ++r) {
                s0[r] = fexp2(s0[r] - m);
                s1[r] = fexp2(s1[r] - m);
                rs += s0[r] + s1[r];
            }
            rs += __shfl_xor(rs, 32);
            l = l * corr + rs;

            // --- pack P into B-fragments (kk-slices of 16) and PV ---
            #pragma unroll
            for (int t2 = 0; t2 < 2; ++t2) {
                f32x16 sv = t2 ? s1 : s0;
                unsigned wv[8], sx[8];
                #pragma unroll
                for (int j = 0; j < 8; ++j) wv[j] = pkbf(sv[2 * j], sv[2 * j + 1]);
                #pragma unroll
                for (int j = 0; j < 8; ++j) sx[j] = __shfl_xor(wv[j], 32);
                #pragma unroll
                for (int u = 0; u < 2; ++u) {
                    union { unsigned u4[4]; bf16x8 v; } pf;
                    pf.u4[0] = hi ? sx[4 * u + 2] : wv[4 * u];
                    pf.u4[1] = hi ? sx[4 * u + 3] : wv[4 * u + 1];
                    pf.u4[2] = hi ? wv[4 * u + 2] : sx[4 * u];
                    pf.u4[3] = hi ? wv[4 * u + 3] : sx[4 * u + 1];
                    int sl = 2 * t2 + u;
                    o0 = __builtin_amdgcn_mfma_f32_32x32x16_bf16(vf[0][sl], pf.v, o0, 0, 0, 0);
                    o1 = __builtin_amdgcn_mfma_f32_32x32x16_bf16(vf[1][sl], pf.v, o1, 0, 0, 0);
                }
            }
        }
        __builtin_amdgcn_s_barrier();
    }

    // --- epilogue: O^T/l -> LDS transpose -> coalesced global stores ---
    float inv = 1.0f / l;
    short* ob = obuf[w];
    #pragma unroll
    for (int r = 0; r < 16; ++r) {
        int d0 = (r & 3) + 8 * (r >> 2) + 4 * hi;
        ob[lo * 64 + ( d0        ^ ((lo & 7) << 3))] = f2bf_bits(o0[r] * inv);
        ob[lo * 64 + ((d0 + 32)  ^ ((lo & 7) << 3))] = f2bf_bits(o1[r] * inv);
    }
    // same-wave LDS read-after-write: compiler inserts lgkmcnt wait
    #pragma unroll
    for (int j = 0; j < 4; ++j) {
        int row = lane >> 1;
        int c8  = ((lane & 1) * 4 + j) * 8;
        bf16x8 v = *reinterpret_cast<const bf16x8*>(
            ob + row * 64 + (c8 ^ ((row & 7) << 3)));
        *reinterpret_cast<bf16x8*>(
            O + (size_t)(b * Tc + q0w + row) * Ec + h * 64 + c8) = v;
    }
}

// ---------------------------------------------------------------------------
extern "C" void kernel_launch(void* const* d_in, const int* in_sizes, int n_in,
                              void* d_out, int out_size, void* d_ws, size_t ws_size,
                              hipStream_t stream)
{
    const float* query = (const float*)d_in[0];
    const float* key   = (const float*)d_in[1];
    const float* value = (const float*)d_in[2];
    const float* cosE  = (const float*)d_in[3];
    const float* sinE  = (const float*)d_in[4];
    // d_in[5] = mask (tril; causality is hard-coded)
    const float* Wq = (const float*)d_in[6];
    const float* bq = (const float*)d_in[7];
    const float* Wk = (const float*)d_in[8];
    const float* bk = (const float*)d_in[9];
    const float* Wv = (const float*)d_in[10];
    const float* bv = (const float*)d_in[11];
    const float* Wo = (const float*)d_in[12];
    const float* bo = (const float*)d_in[13];

    const int M  = Bc * Tc;      // 4096
    const int NK = KVc * Dc;     // 256

    char* ws = (char*)d_ws;
    size_t off = 0;
    auto alloc = [&](size_t bytes) { char* p = ws + off; off += bytes; return p; };

    short* Xq   = (short*)alloc((size_t)M * Ec * 2);
    short* Xk   = (short*)alloc((size_t)M * Ec * 2);
    short* Xv   = (short*)alloc((size_t)M * Ec * 2);
    short* Wqt  = (short*)alloc((size_t)Ec * Ec * 2);
    short* Wkt  = (short*)alloc((size_t)NK * Ec * 2);
    short* Wvt  = (short*)alloc((size_t)NK * Ec * 2);
    short* Wot  = (short*)alloc((size_t)Ec * Ec * 2);
    short* Qp   = (short*)alloc((size_t)M * Ec * 2);
    short* Kp   = (short*)alloc((size_t)M * NK * 2);
    short* VTp  = (short*)alloc((size_t)M * NK * 2);   // [B*KV][64][T]
    short* attn = (short*)alloc((size_t)M * Ec * 2);
    (void)ws_size; // total ~49 MB

    const int nX = M * Ec;   // 4194304
    conv_f32_bf16<<<nX / 4 / 256, 256, 0, stream>>>(query, Xq, nX);
    conv_f32_bf16<<<nX / 4 / 256, 256, 0, stream>>>(key,   Xk, nX);
    conv_f32_bf16<<<nX / 4 / 256, 256, 0, stream>>>(value, Xv, nX);

    transp_conv<<<dim3(Ec / 32, Ec / 32), 256, 0, stream>>>(Wq, Wqt, Ec, Ec);
    transp_conv<<<dim3(NK / 32, Ec / 32), 256, 0, stream>>>(Wk, Wkt, Ec, NK);
    transp_conv<<<dim3(NK / 32, Ec / 32), 256, 0, stream>>>(Wv, Wvt, Ec, NK);
    transp_conv<<<dim3(Ec / 32, Ec / 32), 256, 0, stream>>>(Wo, Wot, Ec, Ec);

    gemm_bf16_nt<short, false><<<dim3(Ec / 64, M / 64), 256, 0, stream>>>(Xq, Wqt, bq, Qp,  M, Ec, Ec);
    gemm_bf16_nt<short, false><<<dim3(NK / 64, M / 64), 256, 0, stream>>>(Xk, Wkt, bk, Kp,  M, NK, Ec);
    gemm_bf16_nt<short, true ><<<dim3(NK / 64, M / 64), 256, 0, stream>>>(Xv, Wvt, bv, VTp, M, NK, Ec);

    // Q: fold 1/sqrt(D) * log2(e) for exp2-domain softmax
    rope_kernel<<<(M * Hc  * 32) / 256, 256, 0, stream>>>(Qp, cosE, sinE, 4, 0.125f * 1.44269504089f);
    rope_kernel<<<(M * KVc * 32) / 256, 256, 0, stream>>>(Kp, cosE, sinE, 2, 1.0f);

    flash_gqa3<<<512, 256, 0, stream>>>(Qp, Kp, VTp, attn);

    gemm_bf16_nt<float, false><<<dim3(Ec / 64, M / 64), 256, 0, stream>>>(
        attn, Wot, bo, (float*)d_out, M, Ec, Ec);
}